// Round 7
// baseline (382.021 us; speedup 1.0000x reference)
//
#include <hip/hip_runtime.h>

// Problem constants: N=50000, E=800000, IN=128, HID=64, OUT=40
#define HID 64
#define JK_DIM 192
#define OUT_DIM 40
#define A_PITCH 68     // gemm_tile A-tile pitch: 16B aligned, max 2-way bank alias
#define FG_PITCH 44    // final_gemm LDS staging pitch (16B-aligned rows)

// ---------------------------------------------------------------------------
// Register-tiled GEMM: out[64x64 tile] = h[64 x K] @ W[K x 64].
// Block = 256 threads -> 16 row-groups x 16 col-groups, thread = 4x4 tile.
// ---------------------------------------------------------------------------
template <int K>
__global__ __launch_bounds__(256) void gemm_tile(const float* __restrict__ h, int inStride,
                                                 const float* __restrict__ W,
                                                 float* __restrict__ out, int outStride,
                                                 int n) {
    __shared__ float As[64 * A_PITCH];
    __shared__ float Ws[64 * HID];
    int tid = threadIdx.x;
    int rg = tid >> 4;
    int cgrp = tid & 15;
    int c0 = cgrp * 4;
    int row0 = blockIdx.x * 64;
    if (row0 >= n) return;

    float acc[4][4] = {{0.f}};

    for (int kb = 0; kb < K; kb += 64) {
        for (int i = tid; i < 64 * 16; i += 256) {
            int r = i >> 4;
            int c4 = (i & 15) * 4;
            int grow = row0 + r;
            if (grow >= n) grow = n - 1;
            float4 v = *(const float4*)(h + (long)grow * inStride + kb + c4);
            *(float4*)(As + r * A_PITCH + c4) = v;
        }
        for (int i = tid; i < 64 * 16; i += 256) {
            int k = i >> 4;
            int c4 = (i & 15) * 4;
            *(float4*)(Ws + k * HID + c4) = *(const float4*)(W + (long)(kb + k) * HID + c4);
        }
        __syncthreads();
#pragma unroll 4
        for (int k = 0; k < 64; k += 4) {
            float4 w0 = *(const float4*)(Ws + (k + 0) * HID + c0);
            float4 w1 = *(const float4*)(Ws + (k + 1) * HID + c0);
            float4 w2 = *(const float4*)(Ws + (k + 2) * HID + c0);
            float4 w3 = *(const float4*)(Ws + (k + 3) * HID + c0);
#pragma unroll
            for (int r = 0; r < 4; ++r) {
                float4 a = *(const float4*)(As + (rg * 4 + r) * A_PITCH + k);
                acc[r][0] += a.x * w0.x + a.y * w1.x + a.z * w2.x + a.w * w3.x;
                acc[r][1] += a.x * w0.y + a.y * w1.y + a.z * w2.y + a.w * w3.y;
                acc[r][2] += a.x * w0.z + a.y * w1.z + a.z * w2.z + a.w * w3.z;
                acc[r][3] += a.x * w0.w + a.y * w1.w + a.z * w2.w + a.w * w3.w;
            }
        }
        __syncthreads();
    }
#pragma unroll
    for (int r = 0; r < 4; ++r) {
        int grow = row0 + rg * 4 + r;
        if (grow < n) {
            float4 o = make_float4(acc[r][0], acc[r][1], acc[r][2], acc[r][3]);
            *(float4*)(out + (long)grow * outStride + c0) = o;
        }
    }
}

// ---------------------------------------------------------------------------
// CSR build: histogram of dst, exclusive scan, atomic-slot fill.
// ---------------------------------------------------------------------------
__global__ __launch_bounds__(256) void hist_dst(const int* __restrict__ dst,
                                                int* __restrict__ deg, int E) {
    int e = blockIdx.x * 256 + threadIdx.x;
    if (e < E) atomicAdd(&deg[dst[e]], 1);
}

__global__ __launch_bounds__(256) void scan_a(const int* __restrict__ deg,
                                              int* __restrict__ off,
                                              int* __restrict__ bsum, int n) {
    __shared__ int tmp[256];
    int i = blockIdx.x * 256 + threadIdx.x;
    int v = (i < n) ? deg[i] : 0;
    tmp[threadIdx.x] = v;
    __syncthreads();
    for (int d = 1; d < 256; d <<= 1) {
        int t = (threadIdx.x >= d) ? tmp[threadIdx.x - d] : 0;
        __syncthreads();
        tmp[threadIdx.x] += t;
        __syncthreads();
    }
    if (i < n) off[i] = tmp[threadIdx.x] - v;
    if (threadIdx.x == 255) bsum[blockIdx.x] = tmp[255];
}

__global__ __launch_bounds__(256) void scan_b(int* __restrict__ bsum, int nblk) {
    __shared__ int tmp[256];
    int v = (threadIdx.x < nblk) ? bsum[threadIdx.x] : 0;
    tmp[threadIdx.x] = v;
    __syncthreads();
    for (int d = 1; d < 256; d <<= 1) {
        int t = (threadIdx.x >= d) ? tmp[threadIdx.x - d] : 0;
        __syncthreads();
        tmp[threadIdx.x] += t;
        __syncthreads();
    }
    if (threadIdx.x < nblk) bsum[threadIdx.x] = tmp[threadIdx.x] - v;
}

__global__ __launch_bounds__(256) void scan_c(int* __restrict__ off,
                                              const int* __restrict__ bsum,
                                              int* __restrict__ pos, int n) {
    int i = blockIdx.x * 256 + threadIdx.x;
    if (i >= n) return;
    int o = off[i] + bsum[blockIdx.x];
    off[i] = o;
    pos[i] = o;
}

__global__ __launch_bounds__(256) void fill_csr(const int* __restrict__ src,
                                                const int* __restrict__ dst,
                                                const float* __restrict__ ew,
                                                int* __restrict__ pos,
                                                int2* __restrict__ ecsr, int E) {
    int e = blockIdx.x * 256 + threadIdx.x;
    if (e >= E) return;
    int p = atomicAdd(&pos[dst[e]], 1);
    int2 v;
    v.x = src[e];
    v.y = __float_as_int(ew[e]);
    ecsr[p] = v;
}

// ---------------------------------------------------------------------------
// Aggregate + bias + ReLU. One wave per dst node (grid-stride).
// Wave = 4 groups x 16 lanes; each group runs TWO edge streams (stride 8)
// with metadata prefetched one iteration ahead -> per iteration the wave has
// 8 independent float4 gathers in flight and no meta->gather serial chain.
// Invalid stream slots carry weight 0 and gather row 0 harmlessly.
// ---------------------------------------------------------------------------
__global__ __launch_bounds__(256) void aggregate(const float* __restrict__ lin,
                                                 const int2* __restrict__ ecsr,
                                                 const int* __restrict__ off,
                                                 const int* __restrict__ deg,
                                                 const float* __restrict__ bias,
                                                 float* __restrict__ hout, int n) {
    int lane = threadIdx.x & 63;
    int g = lane >> 4;          // edge group 0..3
    int cl = lane & 15;         // float4 column slot
    float4 b4 = *(const float4*)(bias + cl * 4);
    int wave = (blockIdx.x * 256 + threadIdx.x) >> 6;
    int nwaves = (gridDim.x * 256) >> 6;
    for (int node = wave; node < n; node += nwaves) {
        int start = off[node];
        int cnt = deg[node];
        float ax = 0.f, ay = 0.f, az = 0.f, aw = 0.f;

        int b = g;
        int sA = 0, sB = 0;
        float wA = 0.f, wB = 0.f;
        if (b < cnt) {
            int2 m = ecsr[start + b];
            sA = m.x; wA = __int_as_float(m.y);
        }
        if (b + 4 < cnt) {
            int2 m = ecsr[start + b + 4];
            sB = m.x; wB = __int_as_float(m.y);
        }
        while (b < cnt) {
            int nb = b + 8;
            int sA2 = 0, sB2 = 0;
            float wA2 = 0.f, wB2 = 0.f;
            if (nb < cnt) {
                int2 m = ecsr[start + nb];
                sA2 = m.x; wA2 = __int_as_float(m.y);
            }
            if (nb + 4 < cnt) {
                int2 m = ecsr[start + nb + 4];
                sB2 = m.x; wB2 = __int_as_float(m.y);
            }
            float4 vA = *(const float4*)(lin + (long)sA * HID + cl * 4);
            float4 vB = *(const float4*)(lin + (long)sB * HID + cl * 4);
            ax += vA.x * wA + vB.x * wB;
            ay += vA.y * wA + vB.y * wB;
            az += vA.z * wA + vB.z * wB;
            aw += vA.w * wA + vB.w * wB;
            sA = sA2; wA = wA2; sB = sB2; wB = wB2;
            b = nb;
        }

        ax += __shfl_xor(ax, 16, 64);
        ay += __shfl_xor(ay, 16, 64);
        az += __shfl_xor(az, 16, 64);
        aw += __shfl_xor(aw, 16, 64);
        ax += __shfl_xor(ax, 32, 64);
        ay += __shfl_xor(ay, 32, 64);
        az += __shfl_xor(az, 32, 64);
        aw += __shfl_xor(aw, 32, 64);
        if (lane < 16) {
            float4 o;
            o.x = fmaxf(ax + b4.x, 0.f);
            o.y = fmaxf(ay + b4.y, 0.f);
            o.z = fmaxf(az + b4.z, 0.f);
            o.w = fmaxf(aw + b4.w, 0.f);
            *(float4*)(hout + (long)node * JK_DIM + cl * 4) = o;
        }
    }
}

// ---------------------------------------------------------------------------
// Transpose Wlin[192,40] -> Wt[40,192] (runs once, 30 KB stays L2-hot).
// ---------------------------------------------------------------------------
__global__ __launch_bounds__(256) void transpose_w(const float* __restrict__ W,
                                                   float* __restrict__ Wt) {
    int i = blockIdx.x * 256 + threadIdx.x;
    if (i < JK_DIM * OUT_DIM) {
        int k = i / OUT_DIM;
        int c = i - k * OUT_DIM;
        Wt[c * JK_DIM + k] = W[i];
    }
}

// ---------------------------------------------------------------------------
// Final: out[n,40] = hcat[n,192] @ Wlin[192,40] + blin.
// 256-thread block covers a 128-row x 40-col tile; thread = 4 rows x 5 cols.
// W read from pre-transposed Wt in global (L2-resident, no LDS conflicts).
// Epilogue stages the tile in LDS (pitch 44) for fully-coalesced float4
// stores (kills the 3x partial-line write amplification).
// ---------------------------------------------------------------------------
__global__ __launch_bounds__(256) void final_gemm(const float* __restrict__ hcat,
                                                  const float* __restrict__ Wt,
                                                  const float* __restrict__ b,
                                                  float* __restrict__ out, int n) {
    __shared__ float Ls[128 * FG_PITCH];  // 22528 B
    int tid = threadIdx.x;
    int rg = tid >> 3;    // 0..31 -> 4 rows each
    int cg = tid & 7;     // 0..7  -> 5 cols each
    int c0 = cg * 5;
    int row0 = blockIdx.x * 128;
    int r0 = row0 + rg * 4;

    const float* hp[4];
#pragma unroll
    for (int r = 0; r < 4; ++r) {
        int rr = r0 + r;
        if (rr >= n) rr = n - 1;
        hp[r] = hcat + (long)rr * JK_DIM;
    }

    float acc[4][5];
#pragma unroll
    for (int r = 0; r < 4; ++r)
#pragma unroll
        for (int i = 0; i < 5; ++i) acc[r][i] = 0.f;

#pragma unroll 2
    for (int k = 0; k < JK_DIM; k += 4) {
        float4 w0 = *(const float4*)(Wt + (c0 + 0) * JK_DIM + k);
        float4 w1 = *(const float4*)(Wt + (c0 + 1) * JK_DIM + k);
        float4 w2 = *(const float4*)(Wt + (c0 + 2) * JK_DIM + k);
        float4 w3 = *(const float4*)(Wt + (c0 + 3) * JK_DIM + k);
        float4 w4 = *(const float4*)(Wt + (c0 + 4) * JK_DIM + k);
#pragma unroll
        for (int r = 0; r < 4; ++r) {
            float4 hv = *(const float4*)(hp[r] + k);
            acc[r][0] += hv.x * w0.x + hv.y * w0.y + hv.z * w0.z + hv.w * w0.w;
            acc[r][1] += hv.x * w1.x + hv.y * w1.y + hv.z * w1.z + hv.w * w1.w;
            acc[r][2] += hv.x * w2.x + hv.y * w2.y + hv.z * w2.z + hv.w * w2.w;
            acc[r][3] += hv.x * w3.x + hv.y * w3.y + hv.z * w3.z + hv.w * w3.w;
            acc[r][4] += hv.x * w4.x + hv.y * w4.y + hv.z * w4.z + hv.w * w4.w;
        }
    }

    // stage to LDS with bias added
#pragma unroll
    for (int r = 0; r < 4; ++r)
#pragma unroll
        for (int i = 0; i < 5; ++i)
            Ls[(rg * 4 + r) * FG_PITCH + c0 + i] = acc[r][i] + b[c0 + i];
    __syncthreads();

    if (row0 + 128 <= n) {
        // coalesced float4 stores over the contiguous 128x40 output region
        for (int i = tid; i < 128 * OUT_DIM / 4; i += 256) {
            int f = i * 4;
            int row = f / OUT_DIM;
            int col = f - row * OUT_DIM;   // always a multiple of 4
            *(float4*)(out + (long)(row0 + row) * OUT_DIM + col) =
                *(const float4*)(Ls + row * FG_PITCH + col);
        }
    } else {
        for (int i = tid; i < 128 * OUT_DIM; i += 256) {
            int row = i / OUT_DIM;
            int col = i - row * OUT_DIM;
            if (row0 + row < n)
                out[(long)(row0 + row) * OUT_DIM + col] = Ls[row * FG_PITCH + col];
        }
    }
}

// ---------------------------------------------------------------------------
extern "C" void kernel_launch(void* const* d_in, const int* in_sizes, int n_in,
                              void* d_out, int out_size, void* d_ws, size_t ws_size,
                              hipStream_t stream) {
    const float* x    = (const float*)d_in[0];
    const int*   ei   = (const int*)d_in[1];
    const float* ew   = (const float*)d_in[2];
    const float* W1   = (const float*)d_in[3];
    const float* b1   = (const float*)d_in[4];
    const float* W2   = (const float*)d_in[5];
    const float* b2   = (const float*)d_in[6];
    const float* W3   = (const float*)d_in[7];
    const float* b3   = (const float*)d_in[8];
    const float* Wlin = (const float*)d_in[9];
    const float* blin = (const float*)d_in[10];
    float* out = (float*)d_out;

    const int N = in_sizes[0] / 128;   // 50000
    const int E = in_sizes[2];         // 800000
    const int* src = ei;
    const int* dst = ei + E;

    // Workspace: lin [N,64] | hcat [N,192] | deg,off,pos [N] | bsum | Wt | ecsr [E]
    char* wsb = (char*)d_ws;
    float* lin  = (float*)wsb;                      wsb += (long)N * HID * 4;
    float* hcat = (float*)wsb;                      wsb += (long)N * JK_DIM * 4;
    int* deg    = (int*)wsb;                        wsb += (long)N * 4;
    int* off    = (int*)wsb;                        wsb += (long)N * 4;
    int* pos    = (int*)wsb;                        wsb += (long)N * 4;
    int* bsum   = (int*)wsb;                        wsb += 256 * 4;
    float* Wt   = (float*)wsb;                      wsb += (long)JK_DIM * OUT_DIM * 4;
    int2* ecsr  = (int2*)wsb;

    dim3 blk(256);
    const int nblkN = (N + 255) / 256;
    dim3 gN(nblkN);
    dim3 gE((E + 255) / 256);
    dim3 gGemm((N + 63) / 64);
    dim3 gAgg(2048);
    dim3 gFin((N + 127) / 128);

    float* h1 = hcat;           // columns [0,64)   of hcat[N,192]
    float* h2 = hcat + HID;     // columns [64,128)
    float* h3 = hcat + 2 * HID; // columns [128,192)

    // ---- CSR build + W transpose (once per launch) ----
    hipMemsetAsync(deg, 0, (long)N * 4, stream);
    hist_dst<<<gE, blk, 0, stream>>>(dst, deg, E);
    scan_a<<<gN, blk, 0, stream>>>(deg, off, bsum, N);
    scan_b<<<1, blk, 0, stream>>>(bsum, nblkN);
    scan_c<<<gN, blk, 0, stream>>>(off, bsum, pos, N);
    fill_csr<<<gE, blk, 0, stream>>>(src, dst, ew, pos, ecsr, E);
    transpose_w<<<(JK_DIM * OUT_DIM + 255) / 256, blk, 0, stream>>>(Wlin, Wt);

    // ---- layer 1 (K=128) ----
    gemm_tile<128><<<gGemm, blk, 0, stream>>>(x, 128, W1, lin, HID, N);
    aggregate<<<gAgg, blk, 0, stream>>>(lin, ecsr, off, deg, b1, h1, N);

    // ---- layer 2 (K=64, reads h1 inside hcat with stride 192) ----
    gemm_tile<64><<<gGemm, blk, 0, stream>>>(h1, JK_DIM, W2, lin, HID, N);
    aggregate<<<gAgg, blk, 0, stream>>>(lin, ecsr, off, deg, b2, h2, N);

    // ---- layer 3 ----
    gemm_tile<64><<<gGemm, blk, 0, stream>>>(h2, JK_DIM, W3, lin, HID, N);
    aggregate<<<gAgg, blk, 0, stream>>>(lin, ecsr, off, deg, b3, h3, N);

    // ---- JK linear ----
    final_gemm<<<gFin, blk, 0, stream>>>(hcat, Wt, blin, out, N);
}

// Round 8
// 359.878 us; speedup vs baseline: 1.0615x; 1.0615x over previous
//
#include <hip/hip_runtime.h>

// Problem constants: N=50000, E=800000, IN=128, HID=64, OUT=40
#define HID 64
#define JK_DIM 192
#define OUT_DIM 40
#define A_PITCH 68     // gemm_tile A-tile pitch: 16B aligned, max 2-way bank alias
#define W_PITCH 196    // final_gemm LDS pitch for Wt rows: b128 reads hit all 32 banks once
#define FG_PITCH 44    // final_gemm epilogue staging pitch

// ---------------------------------------------------------------------------
// Register-tiled GEMM: out[64x64 tile] = h[64 x K] @ W[K x 64].
// Block = 256 threads -> 16 row-groups x 16 col-groups, thread = 4x4 tile.
// ---------------------------------------------------------------------------
template <int K>
__global__ __launch_bounds__(256) void gemm_tile(const float* __restrict__ h, int inStride,
                                                 const float* __restrict__ W,
                                                 float* __restrict__ out, int outStride,
                                                 int n) {
    __shared__ float As[64 * A_PITCH];
    __shared__ float Ws[64 * HID];
    int tid = threadIdx.x;
    int rg = tid >> 4;
    int cgrp = tid & 15;
    int c0 = cgrp * 4;
    int row0 = blockIdx.x * 64;
    if (row0 >= n) return;

    float acc[4][4] = {{0.f}};

    for (int kb = 0; kb < K; kb += 64) {
        for (int i = tid; i < 64 * 16; i += 256) {
            int r = i >> 4;
            int c4 = (i & 15) * 4;
            int grow = row0 + r;
            if (grow >= n) grow = n - 1;
            float4 v = *(const float4*)(h + (long)grow * inStride + kb + c4);
            *(float4*)(As + r * A_PITCH + c4) = v;
        }
        for (int i = tid; i < 64 * 16; i += 256) {
            int k = i >> 4;
            int c4 = (i & 15) * 4;
            *(float4*)(Ws + k * HID + c4) = *(const float4*)(W + (long)(kb + k) * HID + c4);
        }
        __syncthreads();
#pragma unroll 4
        for (int k = 0; k < 64; k += 4) {
            float4 w0 = *(const float4*)(Ws + (k + 0) * HID + c0);
            float4 w1 = *(const float4*)(Ws + (k + 1) * HID + c0);
            float4 w2 = *(const float4*)(Ws + (k + 2) * HID + c0);
            float4 w3 = *(const float4*)(Ws + (k + 3) * HID + c0);
#pragma unroll
            for (int r = 0; r < 4; ++r) {
                float4 a = *(const float4*)(As + (rg * 4 + r) * A_PITCH + k);
                acc[r][0] += a.x * w0.x + a.y * w1.x + a.z * w2.x + a.w * w3.x;
                acc[r][1] += a.x * w0.y + a.y * w1.y + a.z * w2.y + a.w * w3.y;
                acc[r][2] += a.x * w0.z + a.y * w1.z + a.z * w2.z + a.w * w3.z;
                acc[r][3] += a.x * w0.w + a.y * w1.w + a.z * w2.w + a.w * w3.w;
            }
        }
        __syncthreads();
    }
#pragma unroll
    for (int r = 0; r < 4; ++r) {
        int grow = row0 + rg * 4 + r;
        if (grow < n) {
            float4 o = make_float4(acc[r][0], acc[r][1], acc[r][2], acc[r][3]);
            *(float4*)(out + (long)grow * outStride + c0) = o;
        }
    }
}

// ---------------------------------------------------------------------------
// CSR build: histogram of dst, exclusive scan, atomic-slot fill.
// ---------------------------------------------------------------------------
__global__ __launch_bounds__(256) void hist_dst(const int* __restrict__ dst,
                                                int* __restrict__ deg, int E) {
    int e = blockIdx.x * 256 + threadIdx.x;
    if (e < E) atomicAdd(&deg[dst[e]], 1);
}

__global__ __launch_bounds__(256) void scan_a(const int* __restrict__ deg,
                                              int* __restrict__ off,
                                              int* __restrict__ bsum, int n) {
    __shared__ int tmp[256];
    int i = blockIdx.x * 256 + threadIdx.x;
    int v = (i < n) ? deg[i] : 0;
    tmp[threadIdx.x] = v;
    __syncthreads();
    for (int d = 1; d < 256; d <<= 1) {
        int t = (threadIdx.x >= d) ? tmp[threadIdx.x - d] : 0;
        __syncthreads();
        tmp[threadIdx.x] += t;
        __syncthreads();
    }
    if (i < n) off[i] = tmp[threadIdx.x] - v;
    if (threadIdx.x == 255) bsum[blockIdx.x] = tmp[255];
}

__global__ __launch_bounds__(256) void scan_b(int* __restrict__ bsum, int nblk) {
    __shared__ int tmp[256];
    int v = (threadIdx.x < nblk) ? bsum[threadIdx.x] : 0;
    tmp[threadIdx.x] = v;
    __syncthreads();
    for (int d = 1; d < 256; d <<= 1) {
        int t = (threadIdx.x >= d) ? tmp[threadIdx.x - d] : 0;
        __syncthreads();
        tmp[threadIdx.x] += t;
        __syncthreads();
    }
    if (threadIdx.x < nblk) bsum[threadIdx.x] = tmp[threadIdx.x] - v;
}

__global__ __launch_bounds__(256) void scan_c(int* __restrict__ off,
                                              const int* __restrict__ bsum,
                                              int* __restrict__ pos, int n) {
    int i = blockIdx.x * 256 + threadIdx.x;
    if (i >= n) return;
    int o = off[i] + bsum[blockIdx.x];
    off[i] = o;
    pos[i] = o;
}

__global__ __launch_bounds__(256) void fill_csr(const int* __restrict__ src,
                                                const int* __restrict__ dst,
                                                const float* __restrict__ ew,
                                                int* __restrict__ pos,
                                                int2* __restrict__ ecsr, int E) {
    int e = blockIdx.x * 256 + threadIdx.x;
    if (e >= E) return;
    int p = atomicAdd(&pos[dst[e]], 1);
    int2 v;
    v.x = src[e];
    v.y = __float_as_int(ew[e]);
    ecsr[p] = v;
}

// ---------------------------------------------------------------------------
// Aggregate + bias + ReLU. One 16-lane group per node (4 nodes per wave, no
// cross-group reduction). Each group runs a 4-stream software pipeline:
// metadata for the next edge quartet prefetched while the current quartet's
// four float4 gathers are in flight -> 16 independent gathers per wave.
// Invalid slots carry weight 0 and gather row 0 harmlessly.
// ---------------------------------------------------------------------------
__global__ __launch_bounds__(256) void aggregate(const float* __restrict__ lin,
                                                 const int2* __restrict__ ecsr,
                                                 const int* __restrict__ off,
                                                 const int* __restrict__ deg,
                                                 const float* __restrict__ bias,
                                                 float* __restrict__ hout, int n) {
    int cl = threadIdx.x & 15;
    float4 b4 = *(const float4*)(bias + cl * 4);
    int grp = (blockIdx.x * 256 + threadIdx.x) >> 4;
    int ngrp = (gridDim.x * 256) >> 4;
    for (int node = grp; node < n; node += ngrp) {
        int start = off[node];
        int cnt = deg[node];
        float ax = 0.f, ay = 0.f, az = 0.f, aw = 0.f;

        int s[4];
        float w[4];
#pragma unroll
        for (int t = 0; t < 4; ++t) {
            s[t] = 0; w[t] = 0.f;
            if (t < cnt) {
                int2 m = ecsr[start + t];
                s[t] = m.x; w[t] = __int_as_float(m.y);
            }
        }
        for (int bb = 0; bb < cnt; bb += 4) {
            int s2[4];
            float w2[4];
#pragma unroll
            for (int t = 0; t < 4; ++t) {
                int e = bb + 4 + t;
                s2[t] = 0; w2[t] = 0.f;
                if (e < cnt) {
                    int2 m = ecsr[start + e];
                    s2[t] = m.x; w2[t] = __int_as_float(m.y);
                }
            }
            float4 v0 = *(const float4*)(lin + (long)s[0] * HID + cl * 4);
            float4 v1 = *(const float4*)(lin + (long)s[1] * HID + cl * 4);
            float4 v2 = *(const float4*)(lin + (long)s[2] * HID + cl * 4);
            float4 v3 = *(const float4*)(lin + (long)s[3] * HID + cl * 4);
            ax += v0.x * w[0] + v1.x * w[1] + v2.x * w[2] + v3.x * w[3];
            ay += v0.y * w[0] + v1.y * w[1] + v2.y * w[2] + v3.y * w[3];
            az += v0.z * w[0] + v1.z * w[1] + v2.z * w[2] + v3.z * w[3];
            aw += v0.w * w[0] + v1.w * w[1] + v2.w * w[2] + v3.w * w[3];
#pragma unroll
            for (int t = 0; t < 4; ++t) { s[t] = s2[t]; w[t] = w2[t]; }
        }

        float4 o;
        o.x = fmaxf(ax + b4.x, 0.f);
        o.y = fmaxf(ay + b4.y, 0.f);
        o.z = fmaxf(az + b4.z, 0.f);
        o.w = fmaxf(aw + b4.w, 0.f);
        *(float4*)(hout + (long)node * JK_DIM + cl * 4) = o;
    }
}

// ---------------------------------------------------------------------------
// Transpose Wlin[192,40] -> Wt[40,192] (runs once, stays L2-hot).
// ---------------------------------------------------------------------------
__global__ __launch_bounds__(256) void transpose_w(const float* __restrict__ W,
                                                   float* __restrict__ Wt) {
    int i = blockIdx.x * 256 + threadIdx.x;
    if (i < JK_DIM * OUT_DIM) {
        int k = i / OUT_DIM;
        int c = i - k * OUT_DIM;
        Wt[c * JK_DIM + k] = W[i];
    }
}

// ---------------------------------------------------------------------------
// Final: out[n,40] = hcat[n,192] @ Wlin[192,40] + blin.
// 64-row tile per 256-thread block (782 blocks -> 3 blocks/CU resident).
// Thread = 2 rows x 5 cols. Wt staged in LDS at pitch 196: the 8 distinct
// b128 addresses per read cover all 32 banks once, 8-lane same-address
// replication is a broadcast (free). The same LDS pool is reused after the
// K-loop as the epilogue staging buffer for fully-coalesced float4 stores.
// ---------------------------------------------------------------------------
__global__ __launch_bounds__(256) void final_gemm(const float* __restrict__ hcat,
                                                  const float* __restrict__ Wt,
                                                  const float* __restrict__ b,
                                                  float* __restrict__ out, int n) {
    __shared__ float pool[OUT_DIM * W_PITCH];  // 31360 B (>= 64*FG_PITCH for epilogue)
    int tid = threadIdx.x;
    // stage Wt rows (192 floats) at pitch 196 via aligned float4 copies
    for (int i = tid; i < OUT_DIM * 48; i += 256) {
        int c = i / 48;
        int q = (i - c * 48) * 4;
        *(float4*)(pool + c * W_PITCH + q) = *(const float4*)(Wt + (long)c * JK_DIM + q);
    }
    __syncthreads();

    int rg = tid >> 3;    // 0..31 -> 2 rows each
    int cg = tid & 7;     // 0..7  -> 5 cols each
    int c0 = cg * 5;
    int row0 = blockIdx.x * 64;
    int r0 = row0 + rg * 2;
    int ra = r0 < n ? r0 : n - 1;
    int rb = r0 + 1 < n ? r0 + 1 : n - 1;
    const float* ha = hcat + (long)ra * JK_DIM;
    const float* hb = hcat + (long)rb * JK_DIM;

    float acc[2][5];
#pragma unroll
    for (int r = 0; r < 2; ++r)
#pragma unroll
        for (int i = 0; i < 5; ++i) acc[r][i] = 0.f;

#pragma unroll 4
    for (int k = 0; k < JK_DIM; k += 4) {
        float4 va = *(const float4*)(ha + k);
        float4 vb = *(const float4*)(hb + k);
        float4 w0 = *(const float4*)(pool + (c0 + 0) * W_PITCH + k);
        float4 w1 = *(const float4*)(pool + (c0 + 1) * W_PITCH + k);
        float4 w2 = *(const float4*)(pool + (c0 + 2) * W_PITCH + k);
        float4 w3 = *(const float4*)(pool + (c0 + 3) * W_PITCH + k);
        float4 w4 = *(const float4*)(pool + (c0 + 4) * W_PITCH + k);
        acc[0][0] += va.x * w0.x + va.y * w0.y + va.z * w0.z + va.w * w0.w;
        acc[0][1] += va.x * w1.x + va.y * w1.y + va.z * w1.z + va.w * w1.w;
        acc[0][2] += va.x * w2.x + va.y * w2.y + va.z * w2.z + va.w * w2.w;
        acc[0][3] += va.x * w3.x + va.y * w3.y + va.z * w3.z + va.w * w3.w;
        acc[0][4] += va.x * w4.x + va.y * w4.y + va.z * w4.z + va.w * w4.w;
        acc[1][0] += vb.x * w0.x + vb.y * w0.y + vb.z * w0.z + vb.w * w0.w;
        acc[1][1] += vb.x * w1.x + vb.y * w1.y + vb.z * w1.z + vb.w * w1.w;
        acc[1][2] += vb.x * w2.x + vb.y * w2.y + vb.z * w2.z + vb.w * w2.w;
        acc[1][3] += vb.x * w3.x + vb.y * w3.y + vb.z * w3.z + vb.w * w3.w;
        acc[1][4] += vb.x * w4.x + vb.y * w4.y + vb.z * w4.z + vb.w * w4.w;
    }

    // epilogue: reuse pool as 64 x FG_PITCH staging, then coalesced stores
    __syncthreads();
#pragma unroll
    for (int r = 0; r < 2; ++r)
#pragma unroll
        for (int i = 0; i < 5; ++i)
            pool[(rg * 2 + r) * FG_PITCH + c0 + i] = acc[r][i] + b[c0 + i];
    __syncthreads();

    if (row0 + 64 <= n) {
        for (int i = tid; i < 64 * OUT_DIM / 4; i += 256) {
            int f = i * 4;
            int row = f / OUT_DIM;
            int col = f - row * OUT_DIM;
            *(float4*)(out + (long)(row0 + row) * OUT_DIM + col) =
                *(const float4*)(pool + row * FG_PITCH + col);
        }
    } else {
        for (int i = tid; i < 64 * OUT_DIM; i += 256) {
            int row = i / OUT_DIM;
            int col = i - row * OUT_DIM;
            if (row0 + row < n)
                out[(long)(row0 + row) * OUT_DIM + col] = pool[row * FG_PITCH + col];
        }
    }
}

// ---------------------------------------------------------------------------
extern "C" void kernel_launch(void* const* d_in, const int* in_sizes, int n_in,
                              void* d_out, int out_size, void* d_ws, size_t ws_size,
                              hipStream_t stream) {
    const float* x    = (const float*)d_in[0];
    const int*   ei   = (const int*)d_in[1];
    const float* ew   = (const float*)d_in[2];
    const float* W1   = (const float*)d_in[3];
    const float* b1   = (const float*)d_in[4];
    const float* W2   = (const float*)d_in[5];
    const float* b2   = (const float*)d_in[6];
    const float* W3   = (const float*)d_in[7];
    const float* b3   = (const float*)d_in[8];
    const float* Wlin = (const float*)d_in[9];
    const float* blin = (const float*)d_in[10];
    float* out = (float*)d_out;

    const int N = in_sizes[0] / 128;   // 50000
    const int E = in_sizes[2];         // 800000
    const int* src = ei;
    const int* dst = ei + E;

    // Workspace: lin [N,64] | hcat [N,192] | deg,off,pos [N] | bsum | Wt | ecsr [E]
    char* wsb = (char*)d_ws;
    float* lin  = (float*)wsb;                      wsb += (long)N * HID * 4;
    float* hcat = (float*)wsb;                      wsb += (long)N * JK_DIM * 4;
    int* deg    = (int*)wsb;                        wsb += (long)N * 4;
    int* off    = (int*)wsb;                        wsb += (long)N * 4;
    int* pos    = (int*)wsb;                        wsb += (long)N * 4;
    int* bsum   = (int*)wsb;                        wsb += 256 * 4;
    float* Wt   = (float*)wsb;                      wsb += (long)JK_DIM * OUT_DIM * 4;
    int2* ecsr  = (int2*)wsb;

    dim3 blk(256);
    const int nblkN = (N + 255) / 256;
    dim3 gN(nblkN);
    dim3 gE((E + 255) / 256);
    dim3 gGemm((N + 63) / 64);
    dim3 gAgg((N + 15) / 16);              // one 16-lane group per node
    dim3 gFin((N + 63) / 64);

    float* h1 = hcat;           // columns [0,64)   of hcat[N,192]
    float* h2 = hcat + HID;     // columns [64,128)
    float* h3 = hcat + 2 * HID; // columns [128,192)

    // ---- CSR build + W transpose (once per launch) ----
    hipMemsetAsync(deg, 0, (long)N * 4, stream);
    hist_dst<<<gE, blk, 0, stream>>>(dst, deg, E);
    scan_a<<<gN, blk, 0, stream>>>(deg, off, bsum, N);
    scan_b<<<1, blk, 0, stream>>>(bsum, nblkN);
    scan_c<<<gN, blk, 0, stream>>>(off, bsum, pos, N);
    fill_csr<<<gE, blk, 0, stream>>>(src, dst, ew, pos, ecsr, E);
    transpose_w<<<(JK_DIM * OUT_DIM + 255) / 256, blk, 0, stream>>>(Wlin, Wt);

    // ---- layer 1 (K=128) ----
    gemm_tile<128><<<gGemm, blk, 0, stream>>>(x, 128, W1, lin, HID, N);
    aggregate<<<gAgg, blk, 0, stream>>>(lin, ecsr, off, deg, b1, h1, N);

    // ---- layer 2 (K=64, reads h1 inside hcat with stride 192) ----
    gemm_tile<64><<<gGemm, blk, 0, stream>>>(h1, JK_DIM, W2, lin, HID, N);
    aggregate<<<gAgg, blk, 0, stream>>>(lin, ecsr, off, deg, b2, h2, N);

    // ---- layer 3 ----
    gemm_tile<64><<<gGemm, blk, 0, stream>>>(h2, JK_DIM, W3, lin, HID, N);
    aggregate<<<gAgg, blk, 0, stream>>>(lin, ecsr, off, deg, b3, h3, N);

    // ---- JK linear ----
    final_gemm<<<gFin, blk, 0, stream>>>(hcat, Wt, blin, out, N);
}